// Round 4
// baseline (1402.898 us; speedup 1.0000x reference)
//
#include <hip/hip_runtime.h>

// Particles2Grid: SPH cubic-spline splat, B=2, N=100000, C=4, grid 128^3.
// Reference: for each particle, scatter coef*data into 5x5x5 neighborhood,
// coef = sigma * cubic_spline(|center-pos|/h) / (inv_mass * density),
// zero outside grid or q>=1 (skipping those is exact: coef==0).

constexpr int GX = 128, GY = 128, GZ = 128, CH = 4;
constexpr int NC = GX * GY * GZ;
constexpr float STEP   = 0.1f;
constexpr float INV_H  = 5.0f;                    // 1 / 0.2
constexpr float H2     = 0.04f;                   // 0.2^2
constexpr float SIGMA  = 318.30988618379067f;     // 8 / (pi * h^3)

__global__ __launch_bounds__(256) void zero_kernel(float4* __restrict__ out, int n4) {
  int stride = gridDim.x * blockDim.x;
  for (int i = blockIdx.x * blockDim.x + threadIdx.x; i < n4; i += stride)
    out[i] = make_float4(0.f, 0.f, 0.f, 0.f);
}

// One thread per (particle, ox-slab): gridDim.y = 5 gives ox without a divide
// and keeps particle loads perfectly coalesced. Each thread covers a 5x5
// (oy,oz) patch with hierarchical distance culling before sqrt + atomics.
__global__ __launch_bounds__(256) void splat_kernel(
    const float4* __restrict__ locs, const float4* __restrict__ data,
    const float* __restrict__ density, float* __restrict__ out,
    int nTotal, int nPart) {
  int pid = blockIdx.x * blockDim.x + threadIdx.x;
  if (pid >= nTotal) return;
  int ox = blockIdx.y;                  // 0..4

  float4 loc = locs[pid];               // xyz + inv_mass
  float scale = 1.0f / (loc.w * density[pid]);

  int bx = (int)floorf(loc.x / STEP);
  int by = (int)floorf(loc.y / STEP);
  int bz = (int)floorf(loc.z / STEP);

  int cx = bx + ox - 2;
  if ((unsigned)cx >= (unsigned)GX) return;
  float dx  = ((float)cx + 0.5f) * STEP - loc.x;
  float dx2 = dx * dx;
  if (dx2 >= H2) return;

  float4 dat = data[pid];
  int b = (pid >= nPart) ? 1 : 0;       // B == 2
  float* outb = out + (size_t)b * NC * CH;

  for (int oy = 0; oy < 5; ++oy) {
    int cy = by + oy - 2;
    if ((unsigned)cy >= (unsigned)GY) continue;
    float dy = ((float)cy + 0.5f) * STEP - loc.y;
    float dxy2 = dx2 + dy * dy;
    if (dxy2 >= H2) continue;
    float* rowp = outb + (size_t)((cx * GY + cy) * GZ) * CH;
    for (int oz = 0; oz < 5; ++oz) {
      int cz = bz + oz - 2;
      if ((unsigned)cz >= (unsigned)GZ) continue;
      float dz = ((float)cz + 0.5f) * STEP - loc.z;
      float d2 = dxy2 + dz * dz;
      if (d2 >= H2) continue;                 // q >= 1 -> w = 0 exactly
      float q = sqrtf(d2) * INV_H;
      float w = (q < 0.5f)
                  ? (1.0f + 6.0f * q * q * (q - 1.0f))          // 1 - 6q^2 + 6q^3
                  : (2.0f * (1.0f - q) * (1.0f - q) * (1.0f - q));
      float coef = SIGMA * scale * w;
      float* cellp = rowp + cz * CH;
      unsafeAtomicAdd(cellp + 0, coef * dat.x);
      unsafeAtomicAdd(cellp + 1, coef * dat.y);
      unsafeAtomicAdd(cellp + 2, coef * dat.z);
      unsafeAtomicAdd(cellp + 3, coef * dat.w);
    }
  }
}

extern "C" void kernel_launch(void* const* d_in, const int* in_sizes, int n_in,
                              void* d_out, int out_size, void* d_ws, size_t ws_size,
                              hipStream_t stream) {
  const float* locs    = (const float*)d_in[0];   // (B,N,4) f32
  const float* data    = (const float*)d_in[1];   // (B,N,4) f32
  const float* density = (const float*)d_in[2];   // (B,N)   f32
  float* out = (float*)d_out;                      // (B,128,128,128,4) f32

  int nTotal = in_sizes[2];              // B*N = 200000
  int B      = out_size / (NC * CH);     // 2
  int nPart  = nTotal / B;               // 100000

  int n4 = out_size / 4;                 // float4 count (4M)
  int zblocks = min((n4 + 255) / 256, 2048);
  zero_kernel<<<zblocks, 256, 0, stream>>>(
      reinterpret_cast<float4*>(out), n4);

  dim3 grid((nTotal + 255) / 256, 5);
  splat_kernel<<<grid, 256, 0, stream>>>(
      reinterpret_cast<const float4*>(locs),
      reinterpret_cast<const float4*>(data),
      density, out, nTotal, nPart);
}

// Round 5
// 239.924 us; speedup vs baseline: 5.8473x; 5.8473x over previous
//
#include <hip/hip_runtime.h>

// Particles2Grid: SPH cubic-spline splat, B=2, N=100000, C=4, grid 128^3.
// R4 profile showed scatter-atomics are the bottleneck (843 MB of 32B atomic
// transactions, 20 G atomics/s, VALUBusy 1.6%). This version: counting-sort
// particles into 2-cell bins, then per-cell GATHER with zero grid atomics.

constexpr int GX = 128, GY = 128, GZ = 128;
constexpr int NC = GX * GY * GZ;            // 2^21
constexpr int BD = 64;                       // bins per dim (2 cells/bin)
constexpr int NBIN = BD * BD * BD;           // 262144 per batch
constexpr int NB_TOT = 2 * NBIN;             // 524288 (B = 2)
constexpr float STEP   = 0.1f;
constexpr float INV_H  = 5.0f;               // 1 / 0.2
constexpr float H2     = 0.04f;              // 0.2^2
constexpr float SIGMA  = 318.30988618379067f; // 8 / (pi h^3)

// ---------------- fallback path (proven correct in R4) ----------------
__global__ __launch_bounds__(256) void zero_kernel(float4* __restrict__ out, int n4) {
  int stride = gridDim.x * blockDim.x;
  for (int i = blockIdx.x * blockDim.x + threadIdx.x; i < n4; i += stride)
    out[i] = make_float4(0.f, 0.f, 0.f, 0.f);
}

__global__ __launch_bounds__(256) void splat_kernel(
    const float4* __restrict__ locs, const float4* __restrict__ data,
    const float* __restrict__ density, float* __restrict__ out,
    int nTotal, int nPart) {
  int pid = blockIdx.x * blockDim.x + threadIdx.x;
  if (pid >= nTotal) return;
  int ox = blockIdx.y;
  float4 loc = locs[pid];
  float scale = 1.0f / (loc.w * density[pid]);
  int bx = (int)floorf(loc.x / STEP);
  int by = (int)floorf(loc.y / STEP);
  int bz = (int)floorf(loc.z / STEP);
  int cx = bx + ox - 2;
  if ((unsigned)cx >= (unsigned)GX) return;
  float dx = ((float)cx + 0.5f) * STEP - loc.x;
  float dx2 = dx * dx;
  if (dx2 >= H2) return;
  float4 dat = data[pid];
  int b = (pid >= nPart) ? 1 : 0;
  float* outb = out + (size_t)b * NC * 4;
  for (int oy = 0; oy < 5; ++oy) {
    int cy = by + oy - 2;
    if ((unsigned)cy >= (unsigned)GY) continue;
    float dy = ((float)cy + 0.5f) * STEP - loc.y;
    float dxy2 = dx2 + dy * dy;
    if (dxy2 >= H2) continue;
    float* rowp = outb + (size_t)((cx * GY + cy) * GZ) * 4;
    for (int oz = 0; oz < 5; ++oz) {
      int cz = bz + oz - 2;
      if ((unsigned)cz >= (unsigned)GZ) continue;
      float dz = ((float)cz + 0.5f) * STEP - loc.z;
      float d2 = dxy2 + dz * dz;
      if (d2 >= H2) continue;
      float q = sqrtf(d2) * INV_H;
      float w = (q < 0.5f) ? (1.0f + 6.0f * q * q * (q - 1.0f))
                           : (2.0f * (1.0f - q) * (1.0f - q) * (1.0f - q));
      float coef = SIGMA * scale * w;
      float* cellp = rowp + cz * 4;
      unsafeAtomicAdd(cellp + 0, coef * dat.x);
      unsafeAtomicAdd(cellp + 1, coef * dat.y);
      unsafeAtomicAdd(cellp + 2, coef * dat.z);
      unsafeAtomicAdd(cellp + 3, coef * dat.w);
    }
  }
}

// ---------------- binning + gather path ----------------

__device__ __forceinline__ int particle_bin(float4 l, int isB1) {
  int bx = (int)floorf(l.x / STEP);
  int by = (int)floorf(l.y / STEP);
  int bz = (int)floorf(l.z / STEP);
  bx = min(max(bx, 0), GX - 1) >> 1;
  by = min(max(by, 0), GY - 1) >> 1;
  bz = min(max(bz, 0), GZ - 1) >> 1;
  return (isB1 ? NBIN : 0) + ((bx * BD) + by) * BD + bz;
}

__global__ __launch_bounds__(256) void zero_counts(int4* __restrict__ c, int n4) {
  int stride = gridDim.x * blockDim.x;
  for (int i = blockIdx.x * blockDim.x + threadIdx.x; i < n4; i += stride)
    c[i] = make_int4(0, 0, 0, 0);
}

__global__ __launch_bounds__(256) void count_kernel(
    const float4* __restrict__ locs, int* __restrict__ counts,
    int nTotal, int nPart) {
  int pid = blockIdx.x * blockDim.x + threadIdx.x;
  if (pid >= nTotal) return;
  int bin = particle_bin(locs[pid], pid >= nPart);
  atomicAdd(counts + bin, 1);
}

// scan1: 512 blocks x 256 threads x 4 elems. Within-block exclusive scan of
// counts -> starts; block total -> blockSums[bid].
__global__ __launch_bounds__(256) void scan1(
    const int* __restrict__ counts, int* __restrict__ starts,
    int* __restrict__ blockSums) {
  __shared__ int sh[256];
  int t = threadIdx.x, bid = blockIdx.x;
  int base = bid * 1024 + t * 4;
  int4 c = *reinterpret_cast<const int4*>(counts + base);
  int s = c.x + c.y + c.z + c.w;
  sh[t] = s;
  __syncthreads();
  for (int off = 1; off < 256; off <<= 1) {
    int x = (t >= off) ? sh[t - off] : 0;
    __syncthreads();
    sh[t] += x;
    __syncthreads();
  }
  int incl = sh[t];
  int run = incl - s;                      // exclusive
  int4 o;
  o.x = run; run += c.x;
  o.y = run; run += c.y;
  o.z = run; run += c.z;
  o.w = run;
  *reinterpret_cast<int4*>(starts + base) = o;
  if (t == 255) blockSums[bid] = incl;
}

// scan2: single block, 512 threads, exclusive scan of blockSums in place;
// total -> blockSums[512].
__global__ __launch_bounds__(512) void scan2(int* __restrict__ blockSums) {
  __shared__ int sh[512];
  int t = threadIdx.x;
  int v = blockSums[t];
  sh[t] = v;
  __syncthreads();
  for (int off = 1; off < 512; off <<= 1) {
    int x = (t >= off) ? sh[t - off] : 0;
    __syncthreads();
    sh[t] += x;
    __syncthreads();
  }
  int incl = sh[t];
  blockSums[t] = incl - v;                 // exclusive
  if (t == 511) blockSums[512] = incl;     // grand total
}

// scan3: add block offsets; mirror into cursor; append grand total.
__global__ __launch_bounds__(256) void scan3(
    int* __restrict__ starts, const int* __restrict__ blockSums,
    int* __restrict__ cursor) {
  int t = threadIdx.x, bid = blockIdx.x;
  int base = bid * 1024 + t * 4;
  int off = blockSums[bid];
  int4 v = *reinterpret_cast<int4*>(starts + base);
  v.x += off; v.y += off; v.z += off; v.w += off;
  *reinterpret_cast<int4*>(starts + base) = v;
  *reinterpret_cast<int4*>(cursor + base) = v;
  if (bid == 0 && t == 0) starts[NB_TOT] = blockSums[512];
}

__global__ __launch_bounds__(256) void scatter_kernel(
    const float4* __restrict__ locs, const float4* __restrict__ data,
    const float* __restrict__ density, int* __restrict__ cursor,
    float4* __restrict__ sA, float4* __restrict__ sB,
    int nTotal, int nPart) {
  int pid = blockIdx.x * blockDim.x + threadIdx.x;
  if (pid >= nTotal) return;
  float4 l = locs[pid];
  float4 d = data[pid];
  float s = SIGMA / (l.w * density[pid]);
  int bin = particle_bin(l, pid >= nPart);
  int idx = atomicAdd(cursor + bin, 1);
  sA[idx] = make_float4(l.x, l.y, l.z, s * d.x);
  sB[idx] = make_float4(s * d.y, s * d.z, s * d.w, 0.f);
}

// gather: one thread per output cell. 3x3 (x,y) bin pairs, each a contiguous
// particle range over 3 z-bins (z is fastest in bin linearization).
__global__ __launch_bounds__(256) void gather_kernel(
    const int* __restrict__ starts, const float4* __restrict__ sA,
    const float4* __restrict__ sB, float4* __restrict__ out) {
  int tid = blockIdx.x * blockDim.x + threadIdx.x;
  if (tid >= 2 * NC) return;
  int b    = tid >> 21;                    // NC = 2^21
  int cell = tid & (NC - 1);
  int cx = cell >> 14;
  int cy = (cell >> 7) & 127;
  int cz = cell & 127;
  float px = ((float)cx + 0.5f) * STEP;
  float py = ((float)cy + 0.5f) * STEP;
  float pz = ((float)cz + 0.5f) * STEP;
  int lx = max(cx - 2, 0) >> 1, hx = min(cx + 2, GX - 1) >> 1;
  int ly = max(cy - 2, 0) >> 1, hy = min(cy + 2, GY - 1) >> 1;
  int lz = max(cz - 2, 0) >> 1, hz = min(cz + 2, GZ - 1) >> 1;
  int bb = b ? NBIN : 0;
  float ax = 0.f, ay = 0.f, az = 0.f, aw = 0.f;
  for (int ix = lx; ix <= hx; ++ix) {
    for (int iy = ly; iy <= hy; ++iy) {
      int base = bb + ((ix * BD) + iy) * BD;
      int s = starts[base + lz];
      int e = starts[base + hz + 1];
      for (int p = s; p < e; ++p) {
        float4 a = sA[p];
        float dx = a.x - px, dy = a.y - py, dz = a.z - pz;
        float d2 = fmaf(dx, dx, fmaf(dy, dy, dz * dz));
        if (d2 < H2) {
          float q = sqrtf(d2) * INV_H;
          float w = (q < 0.5f) ? (1.0f + 6.0f * q * q * (q - 1.0f))
                               : (2.0f * (1.0f - q) * (1.0f - q) * (1.0f - q));
          float4 v = sB[p];
          ax = fmaf(w, a.w, ax);
          ay = fmaf(w, v.x, ay);
          az = fmaf(w, v.y, az);
          aw = fmaf(w, v.z, aw);
        }
      }
    }
  }
  out[tid] = make_float4(ax, ay, az, aw);
}

// ---------------- launch ----------------
static inline size_t align_up(size_t x, size_t a) { return (x + a - 1) & ~(a - 1); }

extern "C" void kernel_launch(void* const* d_in, const int* in_sizes, int n_in,
                              void* d_out, int out_size, void* d_ws, size_t ws_size,
                              hipStream_t stream) {
  const float* locs    = (const float*)d_in[0];   // (B,N,4) f32
  const float* data    = (const float*)d_in[1];   // (B,N,4) f32
  const float* density = (const float*)d_in[2];   // (B,N)   f32
  float* out = (float*)d_out;                      // (B,128,128,128,4) f32

  int nTotal = in_sizes[2];              // B*N = 200000
  int B      = out_size / (NC * 4);      // 2
  int nPart  = nTotal / B;               // 100000

  // workspace layout
  size_t o_counts = 0;
  size_t o_starts = align_up(o_counts + sizeof(int) * NB_TOT, 256);
  size_t o_cursor = align_up(o_starts + sizeof(int) * (NB_TOT + 1), 256);
  size_t o_bsums  = align_up(o_cursor + sizeof(int) * NB_TOT, 256);
  size_t o_sA     = align_up(o_bsums + sizeof(int) * 513, 256);
  size_t o_sB     = align_up(o_sA + sizeof(float4) * (size_t)nTotal, 256);
  size_t need     = o_sB + sizeof(float4) * (size_t)nTotal;

  if (B != 2 || ws_size < need) {
    // fallback: proven scatter-atomic path
    int n4 = out_size / 4;
    int zblocks = min((n4 + 255) / 256, 2048);
    zero_kernel<<<zblocks, 256, 0, stream>>>(reinterpret_cast<float4*>(out), n4);
    dim3 grid((nTotal + 255) / 256, 5);
    splat_kernel<<<grid, 256, 0, stream>>>(
        reinterpret_cast<const float4*>(locs),
        reinterpret_cast<const float4*>(data), density, out, nTotal, nPart);
    return;
  }

  char* ws = (char*)d_ws;
  int* counts   = (int*)(ws + o_counts);
  int* starts   = (int*)(ws + o_starts);
  int* cursor   = (int*)(ws + o_cursor);
  int* bsums    = (int*)(ws + o_bsums);
  float4* sA    = (float4*)(ws + o_sA);
  float4* sB    = (float4*)(ws + o_sB);

  int pblocks = (nTotal + 255) / 256;

  zero_counts<<<512, 256, 0, stream>>>((int4*)counts, NB_TOT / 4);
  count_kernel<<<pblocks, 256, 0, stream>>>(
      reinterpret_cast<const float4*>(locs), counts, nTotal, nPart);
  scan1<<<512, 256, 0, stream>>>(counts, starts, bsums);
  scan2<<<1, 512, 0, stream>>>(bsums);
  scan3<<<512, 256, 0, stream>>>(starts, bsums, cursor);
  scatter_kernel<<<pblocks, 256, 0, stream>>>(
      reinterpret_cast<const float4*>(locs),
      reinterpret_cast<const float4*>(data), density, cursor, sA, sB,
      nTotal, nPart);
  gather_kernel<<<(2 * NC) / 256, 256, 0, stream>>>(
      starts, sA, sB, reinterpret_cast<float4*>(out));
}

// Round 6
// 176.865 us; speedup vs baseline: 7.9320x; 1.3565x over previous
//
#include <hip/hip_runtime.h>

// Particles2Grid: SPH cubic-spline splat, B=2, N=100000, C=4, grid 128^3.
// R4: scatter-atomics bound (843 MB of 32B atomic txns). R5: bin+gather,
// 240 us total, gather 141 us VALU/divergence-bound (VALUBusy 72%, HBM 7%).
// R6: 8-cells-per-thread gather (2x2x2 cell block shares one bin window) to
// amortize candidate loop 8x; scan2 folded into scan3.

constexpr int GX = 128, GY = 128, GZ = 128;
constexpr int NC = GX * GY * GZ;            // 2^21
constexpr int BD = 64;                       // bins per dim (2 cells/bin)
constexpr int NBIN = BD * BD * BD;           // 262144 per batch
constexpr int NB_TOT = 2 * NBIN;             // 524288 (B = 2)
constexpr float STEP   = 0.1f;
constexpr float INV_H  = 5.0f;               // 1 / 0.2
constexpr float H2     = 0.04f;              // 0.2^2
constexpr float SIGMA  = 318.30988618379067f; // 8 / (pi h^3)

// ---------------- fallback path (proven correct in R4) ----------------
__global__ __launch_bounds__(256) void zero_kernel(float4* __restrict__ out, int n4) {
  int stride = gridDim.x * blockDim.x;
  for (int i = blockIdx.x * blockDim.x + threadIdx.x; i < n4; i += stride)
    out[i] = make_float4(0.f, 0.f, 0.f, 0.f);
}

__global__ __launch_bounds__(256) void splat_kernel(
    const float4* __restrict__ locs, const float4* __restrict__ data,
    const float* __restrict__ density, float* __restrict__ out,
    int nTotal, int nPart) {
  int pid = blockIdx.x * blockDim.x + threadIdx.x;
  if (pid >= nTotal) return;
  int ox = blockIdx.y;
  float4 loc = locs[pid];
  float scale = 1.0f / (loc.w * density[pid]);
  int bx = (int)floorf(loc.x / STEP);
  int by = (int)floorf(loc.y / STEP);
  int bz = (int)floorf(loc.z / STEP);
  int cx = bx + ox - 2;
  if ((unsigned)cx >= (unsigned)GX) return;
  float dx = ((float)cx + 0.5f) * STEP - loc.x;
  float dx2 = dx * dx;
  if (dx2 >= H2) return;
  float4 dat = data[pid];
  int b = (pid >= nPart) ? 1 : 0;
  float* outb = out + (size_t)b * NC * 4;
  for (int oy = 0; oy < 5; ++oy) {
    int cy = by + oy - 2;
    if ((unsigned)cy >= (unsigned)GY) continue;
    float dy = ((float)cy + 0.5f) * STEP - loc.y;
    float dxy2 = dx2 + dy * dy;
    if (dxy2 >= H2) continue;
    float* rowp = outb + (size_t)((cx * GY + cy) * GZ) * 4;
    for (int oz = 0; oz < 5; ++oz) {
      int cz = bz + oz - 2;
      if ((unsigned)cz >= (unsigned)GZ) continue;
      float dz = ((float)cz + 0.5f) * STEP - loc.z;
      float d2 = dxy2 + dz * dz;
      if (d2 >= H2) continue;
      float q = sqrtf(d2) * INV_H;
      float w = (q < 0.5f) ? (1.0f + 6.0f * q * q * (q - 1.0f))
                           : (2.0f * (1.0f - q) * (1.0f - q) * (1.0f - q));
      float coef = SIGMA * scale * w;
      float* cellp = rowp + cz * 4;
      unsafeAtomicAdd(cellp + 0, coef * dat.x);
      unsafeAtomicAdd(cellp + 1, coef * dat.y);
      unsafeAtomicAdd(cellp + 2, coef * dat.z);
      unsafeAtomicAdd(cellp + 3, coef * dat.w);
    }
  }
}

// ---------------- binning + gather path ----------------

__device__ __forceinline__ int particle_bin(float4 l, int isB1) {
  int bx = (int)floorf(l.x / STEP);
  int by = (int)floorf(l.y / STEP);
  int bz = (int)floorf(l.z / STEP);
  bx = min(max(bx, 0), GX - 1) >> 1;
  by = min(max(by, 0), GY - 1) >> 1;
  bz = min(max(bz, 0), GZ - 1) >> 1;
  return (isB1 ? NBIN : 0) + ((bx * BD) + by) * BD + bz;
}

__global__ __launch_bounds__(256) void zero_counts(int4* __restrict__ c, int n4) {
  int stride = gridDim.x * blockDim.x;
  for (int i = blockIdx.x * blockDim.x + threadIdx.x; i < n4; i += stride)
    c[i] = make_int4(0, 0, 0, 0);
}

__global__ __launch_bounds__(256) void count_kernel(
    const float4* __restrict__ locs, int* __restrict__ counts,
    int nTotal, int nPart) {
  int pid = blockIdx.x * blockDim.x + threadIdx.x;
  if (pid >= nTotal) return;
  int bin = particle_bin(locs[pid], pid >= nPart);
  atomicAdd(counts + bin, 1);
}

// scan1: 512 blocks x 256 threads x 4 elems. Within-block exclusive scan of
// counts -> starts; block total -> blockSums[bid].
__global__ __launch_bounds__(256) void scan1(
    const int* __restrict__ counts, int* __restrict__ starts,
    int* __restrict__ blockSums) {
  __shared__ int sh[256];
  int t = threadIdx.x, bid = blockIdx.x;
  int base = bid * 1024 + t * 4;
  int4 c = *reinterpret_cast<const int4*>(counts + base);
  int s = c.x + c.y + c.z + c.w;
  sh[t] = s;
  __syncthreads();
  for (int off = 1; off < 256; off <<= 1) {
    int x = (t >= off) ? sh[t - off] : 0;
    __syncthreads();
    sh[t] += x;
    __syncthreads();
  }
  int incl = sh[t];
  int run = incl - s;                      // exclusive
  int4 o;
  o.x = run; run += c.x;
  o.y = run; run += c.y;
  o.z = run; run += c.z;
  o.w = run;
  *reinterpret_cast<int4*>(starts + base) = o;
  if (t == 255) blockSums[bid] = incl;
}

// scan3: each block computes its own prefix offset by reducing
// blockSums[0..bid) (512 ints, trivially parallel), adds it, mirrors into
// cursor. Block 511 thread 0 also writes the grand total to starts[NB_TOT].
__global__ __launch_bounds__(256) void scan3(
    int* __restrict__ starts, const int* __restrict__ blockSums,
    int* __restrict__ cursor) {
  __shared__ int red[8];
  int t = threadIdx.x, bid = blockIdx.x;
  int part = ((t < bid) ? blockSums[t] : 0) +
             ((t + 256 < bid) ? blockSums[t + 256] : 0);
  for (int o = 32; o > 0; o >>= 1) part += __shfl_down(part, o);
  if ((t & 63) == 0) red[t >> 6] = part;
  __syncthreads();
  if (t == 0) red[0] = red[0] + red[1] + red[2] + red[3];
  __syncthreads();
  int off = red[0];
  int base = bid * 1024 + t * 4;
  int4 v = *reinterpret_cast<int4*>(starts + base);
  v.x += off; v.y += off; v.z += off; v.w += off;
  *reinterpret_cast<int4*>(starts + base) = v;
  *reinterpret_cast<int4*>(cursor + base) = v;
  if (bid == 511 && t == 0) starts[NB_TOT] = off + blockSums[511];
}

__global__ __launch_bounds__(256) void scatter_kernel(
    const float4* __restrict__ locs, const float4* __restrict__ data,
    const float* __restrict__ density, int* __restrict__ cursor,
    float4* __restrict__ sA, float4* __restrict__ sB,
    int nTotal, int nPart) {
  int pid = blockIdx.x * blockDim.x + threadIdx.x;
  if (pid >= nTotal) return;
  float4 l = locs[pid];
  float4 d = data[pid];
  float s = SIGMA / (l.w * density[pid]);
  int bin = particle_bin(l, pid >= nPart);
  int idx = atomicAdd(cursor + bin, 1);
  sA[idx] = make_float4(l.x, l.y, l.z, s * d.x);
  sB[idx] = make_float4(s * d.y, s * d.z, s * d.w, 0.f);
}

// gather8: one thread per 2x2x2 cell block. Cells 2k,2k+1 share the bin
// window [k-1,k+1] per dim, so one candidate loop feeds 8 cells: per-axis
// distance squares computed once, 8 combine+spline, 32 accumulators in VGPRs.
__global__ __launch_bounds__(256) void gather8_kernel(
    const int* __restrict__ starts, const float4* __restrict__ sA,
    const float4* __restrict__ sB, float4* __restrict__ out) {
  int tid = blockIdx.x * blockDim.x + threadIdx.x;   // 2 * 64^3
  int b   = tid >> 18;
  int blk = tid & ((1 << 18) - 1);
  int Bz = blk & 63;
  int By = (blk >> 6) & 63;
  int Bx = blk >> 12;

  int cx0 = 2 * Bx, cy0 = 2 * By, cz0 = 2 * Bz;
  float px0 = ((float)cx0 + 0.5f) * STEP;
  float px1 = ((float)(cx0 + 1) + 0.5f) * STEP;
  float py0 = ((float)cy0 + 0.5f) * STEP;
  float py1 = ((float)(cy0 + 1) + 0.5f) * STEP;
  float pz0 = ((float)cz0 + 0.5f) * STEP;
  float pz1 = ((float)(cz0 + 1) + 0.5f) * STEP;

  int lx = max(Bx - 1, 0), hx = min(Bx + 1, BD - 1);
  int ly = max(By - 1, 0), hy = min(By + 1, BD - 1);
  int lz = max(Bz - 1, 0), hz = min(Bz + 1, BD - 1);
  int bb = b ? NBIN : 0;

  float acc[2][2][2][4];
#pragma unroll
  for (int i = 0; i < 2; ++i)
#pragma unroll
    for (int j = 0; j < 2; ++j)
#pragma unroll
      for (int k = 0; k < 2; ++k)
#pragma unroll
        for (int c = 0; c < 4; ++c) acc[i][j][k][c] = 0.f;

  for (int ix = lx; ix <= hx; ++ix) {
    for (int iy = ly; iy <= hy; ++iy) {
      int base = bb + (((ix << 6) + iy) << 6);
      int s = starts[base + lz];
      int e = starts[base + hz + 1];
      for (int p = s; p < e; ++p) {
        float4 a = sA[p];
        float4 v = sB[p];
        float dx0 = a.x - px0, dx1 = a.x - px1;
        float dy0 = a.y - py0, dy1 = a.y - py1;
        float dz0 = a.z - pz0, dz1 = a.z - pz1;
        float dx2[2] = {dx0 * dx0, dx1 * dx1};
        float dy2[2] = {dy0 * dy0, dy1 * dy1};
        float dz2[2] = {dz0 * dz0, dz1 * dz1};
#pragma unroll
        for (int i = 0; i < 2; ++i) {
#pragma unroll
          for (int j = 0; j < 2; ++j) {
            float dxy = dx2[i] + dy2[j];
#pragma unroll
            for (int k = 0; k < 2; ++k) {
              float d2 = dxy + dz2[k];
              if (d2 < H2) {
                float q = sqrtf(d2) * INV_H;
                float om = 1.0f - q;
                float wh = 2.0f * om * om * om;
                float wl = fmaf(6.0f * q * q, q - 1.0f, 1.0f);
                float w = (q < 0.5f) ? wl : wh;
                acc[i][j][k][0] = fmaf(w, a.w, acc[i][j][k][0]);
                acc[i][j][k][1] = fmaf(w, v.x, acc[i][j][k][1]);
                acc[i][j][k][2] = fmaf(w, v.y, acc[i][j][k][2]);
                acc[i][j][k][3] = fmaf(w, v.z, acc[i][j][k][3]);
              }
            }
          }
        }
      }
    }
  }

#pragma unroll
  for (int i = 0; i < 2; ++i)
#pragma unroll
    for (int j = 0; j < 2; ++j)
#pragma unroll
      for (int k = 0; k < 2; ++k) {
        int cell = (((cx0 + i) * GY) + (cy0 + j)) * GZ + (cz0 + k);
        out[((size_t)b << 21) + cell] =
            make_float4(acc[i][j][k][0], acc[i][j][k][1],
                        acc[i][j][k][2], acc[i][j][k][3]);
      }
}

// ---------------- launch ----------------
static inline size_t align_up(size_t x, size_t a) { return (x + a - 1) & ~(a - 1); }

extern "C" void kernel_launch(void* const* d_in, const int* in_sizes, int n_in,
                              void* d_out, int out_size, void* d_ws, size_t ws_size,
                              hipStream_t stream) {
  const float* locs    = (const float*)d_in[0];   // (B,N,4) f32
  const float* data    = (const float*)d_in[1];   // (B,N,4) f32
  const float* density = (const float*)d_in[2];   // (B,N)   f32
  float* out = (float*)d_out;                      // (B,128,128,128,4) f32

  int nTotal = in_sizes[2];              // B*N = 200000
  int B      = out_size / (NC * 4);      // 2
  int nPart  = nTotal / B;               // 100000

  // workspace layout
  size_t o_counts = 0;
  size_t o_starts = align_up(o_counts + sizeof(int) * NB_TOT, 256);
  size_t o_cursor = align_up(o_starts + sizeof(int) * (NB_TOT + 1), 256);
  size_t o_bsums  = align_up(o_cursor + sizeof(int) * NB_TOT, 256);
  size_t o_sA     = align_up(o_bsums + sizeof(int) * 513, 256);
  size_t o_sB     = align_up(o_sA + sizeof(float4) * (size_t)nTotal, 256);
  size_t need     = o_sB + sizeof(float4) * (size_t)nTotal;

  if (B != 2 || ws_size < need) {
    // fallback: proven scatter-atomic path
    int n4 = out_size / 4;
    int zblocks = min((n4 + 255) / 256, 2048);
    zero_kernel<<<zblocks, 256, 0, stream>>>(reinterpret_cast<float4*>(out), n4);
    dim3 grid((nTotal + 255) / 256, 5);
    splat_kernel<<<grid, 256, 0, stream>>>(
        reinterpret_cast<const float4*>(locs),
        reinterpret_cast<const float4*>(data), density, out, nTotal, nPart);
    return;
  }

  char* ws = (char*)d_ws;
  int* counts   = (int*)(ws + o_counts);
  int* starts   = (int*)(ws + o_starts);
  int* cursor   = (int*)(ws + o_cursor);
  int* bsums    = (int*)(ws + o_bsums);
  float4* sA    = (float4*)(ws + o_sA);
  float4* sB    = (float4*)(ws + o_sB);

  int pblocks = (nTotal + 255) / 256;

  zero_counts<<<512, 256, 0, stream>>>((int4*)counts, NB_TOT / 4);
  count_kernel<<<pblocks, 256, 0, stream>>>(
      reinterpret_cast<const float4*>(locs), counts, nTotal, nPart);
  scan1<<<512, 256, 0, stream>>>(counts, starts, bsums);
  scan3<<<512, 256, 0, stream>>>(starts, bsums, cursor);
  scatter_kernel<<<pblocks, 256, 0, stream>>>(
      reinterpret_cast<const float4*>(locs),
      reinterpret_cast<const float4*>(data), density, cursor, sA, sB,
      nTotal, nPart);
  gather8_kernel<<<(2 * NBIN) / 256, 256, 0, stream>>>(
      starts, sA, sB, reinterpret_cast<float4*>(out));
}